// Round 2
// baseline (156.288 us; speedup 1.0000x reference)
//
#include <hip/hip_runtime.h>

#define CC 8
#define HH 256
#define WW 512
#define KK 9
// LDS row stride: 520 floats needed (w in [-4, 516)), padded to 532 (16B-divisible)
#define XS_STRIDE 532

__global__ __launch_bounds__(256) void dynfilter_kernel(
    const float* __restrict__ x,
    const float* __restrict__ filt,
    const float* __restrict__ fbias,
    float* __restrict__ out)
{
    __shared__ __align__(16) float xs[CC][XS_STRIDE];

    const int tid = threadIdx.x;
    const int bid = blockIdx.x;
    const int n = bid >> 8;       // grid = N*H = 512
    const int h = bid & 255;
    const int w0 = tid << 1;      // 2 pixels per thread, covers W=512 with 256 threads

    const int lane32 = tid & 31;  // staging: 8 c-groups x 32 lanes
    const int cstage = tid >> 5;

    float acc0[CC], acc1[CC];
    {
        const float2 fb = *(const float2*)(fbias + (n * HH + h) * WW + w0);
        #pragma unroll
        for (int c = 0; c < CC; ++c) { acc0[c] = fb.x; acc1[c] = fb.y; }
    }

    const float* xcbase = x + ((size_t)(n * CC + cstage)) * HH * WW;

    for (int i = 0; i < KK; ++i) {
        const int hh = h + i - 4;
        const bool rowok = (hh >= 0) && (hh < HH);

        __syncthreads();
        // Stage x row (all 8 channels, zero-padded halo) into LDS.
        // 130 float4 per channel covering w in [-4, 516).
        const float4* src = (const float4*)(xcbase + hh * WW);
        #pragma unroll
        for (int it = 0; it < 5; ++it) {
            const int k = lane32 + (it << 5);
            if (k < 130) {
                const int w = (k << 2) - 4;
                float4 v = make_float4(0.f, 0.f, 0.f, 0.f);
                if (rowok && (unsigned)w < (unsigned)WW) v = src[w >> 2];
                *(float4*)&xs[cstage][w + 4] = v;   // float index w+4 = 4k -> 16B aligned
            }
        }
        __syncthreads();

        // Filter taps for this tap-row: 9 coalesced float2 loads (the HBM-critical stream)
        const float* frow = filt + ((size_t)(n * 81 + i * KK) * HH + h) * WW + w0;
        float2 fr[KK];
        #pragma unroll
        for (int j = 0; j < KK; ++j)
            fr[j] = *(const float2*)(frow + (size_t)j * (HH * WW));

        #pragma unroll
        for (int c = 0; c < CC; ++c) {
            float xr[10];
            #pragma unroll
            for (int s = 0; s < 5; ++s)
                *(float2*)&xr[2 * s] = *(const float2*)&xs[c][w0 + 2 * s];
            #pragma unroll
            for (int j = 0; j < KK; ++j) {
                acc0[c] = fmaf(fr[j].x, xr[j],     acc0[c]);
                acc1[c] = fmaf(fr[j].y, xr[j + 1], acc1[c]);
            }
        }
    }

    #pragma unroll
    for (int c = 0; c < CC; ++c) {
        *(float2*)(out + ((size_t)(n * CC + c) * HH + h) * WW + w0) =
            make_float2(acc0[c], acc1[c]);
    }
}

extern "C" void kernel_launch(void* const* d_in, const int* in_sizes, int n_in,
                              void* d_out, int out_size, void* d_ws, size_t ws_size,
                              hipStream_t stream) {
    const float* x  = (const float*)d_in[0];
    const float* f  = (const float*)d_in[1];
    const float* fb = (const float*)d_in[2];
    float* o = (float*)d_out;
    hipLaunchKernelGGL(dynfilter_kernel, dim3(2 * HH), dim3(256), 0, stream,
                       x, f, fb, o);
}